// Round 1
// baseline (323.707 us; speedup 1.0000x reference)
//
#include <hip/hip_runtime.h>

constexpr int BATCH = 2048;
constexpr int NHID  = 512;
constexpr int H0    = 256;
constexpr int H1    = 256;

// One block per sample. 256 threads = 4 waves.
// Matmul phase: wave g handles d in [g*128, (g+1)*128); lane l accumulates
// classes 4l..4l+3 via float4 weight loads (16B/lane coalesced).
// Partials reduced through LDS; softmax via wave shuffles + LDS cross-wave.
__global__ __launch_bounds__(256, 8) void hs_fused(
    const float* __restrict__ x,        // [B, NHID]
    const int*   __restrict__ labels,   // [B]
    const int*   __restrict__ parents,  // [B]
    const float* __restrict__ topW,     // [NHID, H0] row-major
    const float* __restrict__ topb,     // [H0]
    const float* __restrict__ botW,     // [H0, NHID, H1]
    const float* __restrict__ botb,     // [H0, H1]
    float*       __restrict__ out)      // [B]
{
    const int b = blockIdx.x;
    const int t = threadIdx.x;        // 0..255
    const int g = t >> 6;             // wave id 0..3
    const int l = t & 63;             // lane

    __shared__ __align__(16) float xs[NHID];      // 2 KB input row
    __shared__ __align__(16) float part[4][H0];   // 4 KB partial logits
    __shared__ float red[4];
    __shared__ float scal[2];                     // p_top, p_bot

    // load input row: 512 floats as float2 per thread
    {
        const float2* xr = (const float2*)(x + (size_t)b * NHID);
        ((float2*)xs)[t] = xr[t];
    }
    const int parent = parents[b];
    const int label  = labels[b];
    __syncthreads();

    for (int pass = 0; pass < 2; ++pass) {
        const float* W    = (pass == 0) ? topW
                                        : botW + (size_t)parent * NHID * H1;
        const float* bias = (pass == 0) ? topb
                                        : botb + (size_t)parent * H1;

        // ---- partial GEMV: 128 K-steps, 4 classes per lane
        float4 acc = make_float4(0.f, 0.f, 0.f, 0.f);
        const float* Wp = W + (size_t)(g * 128) * 256 + 4 * l;
        #pragma unroll 8
        for (int d = 0; d < 128; ++d) {
            const float  xv = xs[g * 128 + d];
            const float4 w  = *(const float4*)Wp;
            Wp += 256;
            acc.x = fmaf(xv, w.x, acc.x);
            acc.y = fmaf(xv, w.y, acc.y);
            acc.z = fmaf(xv, w.z, acc.z);
            acc.w = fmaf(xv, w.w, acc.w);
        }
        *(float4*)&part[g][4 * l] = acc;
        __syncthreads();

        // ---- thread t owns class t: combine partials + bias
        const float logit = part[0][t] + part[1][t] + part[2][t] + part[3][t]
                          + bias[t];

        // ---- block softmax (max)
        float m = logit;
        #pragma unroll
        for (int off = 32; off > 0; off >>= 1)
            m = fmaxf(m, __shfl_xor(m, off, 64));
        if (l == 0) red[g] = m;
        __syncthreads();
        m = fmaxf(fmaxf(red[0], red[1]), fmaxf(red[2], red[3]));

        // ---- block softmax (sum of exp)
        const float e = expf(logit - m);
        float s = e;
        #pragma unroll
        for (int off = 32; off > 0; off >>= 1)
            s += __shfl_xor(s, off, 64);
        __syncthreads();              // all lanes done reading red (max) before overwrite
        if (l == 0) red[g] = s;
        __syncthreads();
        s = red[0] + red[1] + red[2] + red[3];

        const int tgt = (pass == 0) ? parent : label;
        if (t == tgt) scal[pass] = e / s;
        __syncthreads();              // scal visible; part[]/red[] safe to reuse
    }

    if (t == 0) out[b] = scal[0] * scal[1];
}

extern "C" void kernel_launch(void* const* d_in, const int* in_sizes, int n_in,
                              void* d_out, int out_size, void* d_ws, size_t ws_size,
                              hipStream_t stream) {
    const float* x       = (const float*)d_in[0];
    const int*   labels  = (const int*)  d_in[1];
    const int*   parents = (const int*)  d_in[2];
    const float* topW    = (const float*)d_in[3];
    const float* topb    = (const float*)d_in[4];
    const float* botW    = (const float*)d_in[5];
    const float* botb    = (const float*)d_in[6];
    float*       out     = (float*)d_out;

    hs_fused<<<BATCH, 256, 0, stream>>>(x, labels, parents,
                                        topW, topb, botW, botb, out);
}

// Round 3
// 272.170 us; speedup vs baseline: 1.1894x; 1.1894x over previous
//
#include <hip/hip_runtime.h>

constexpr int BATCH = 2048;
constexpr int NHID  = 512;
constexpr int H0    = 256;
constexpr int H1    = 256;
constexpr int S     = 8;    // samples per register tile

// One block (256 thr = 4 waves) per parent class p. Block gathers its samples,
// then per 8-sample tile streams topW / botW[p] ONCE:
//   matmul: wave g covers d in [128g,128g+128), lane l classes 4l..4l+3
//   (float4 weight loads, 1KB/wave/step coalesced), partials -> LDS.
// Softmax: Round-1-proven structure — thread t owns class t, block reduce via
// wave shuffle + per-wave LDS cells, expf, one sample at a time.
__global__ __launch_bounds__(256) void hs_grouped(
    const float* __restrict__ x,        // [B, NHID]
    const int*   __restrict__ labels,   // [B]
    const int*   __restrict__ parents,  // [B]
    const float* __restrict__ topW,     // [NHID, H0]
    const float* __restrict__ topb,     // [H0]
    const float* __restrict__ botW,     // [H0, NHID, H1]
    const float* __restrict__ botb,     // [H0, H1]
    float*       __restrict__ out)      // [B]
{
    const int p = blockIdx.x;
    const int t = threadIdx.x;
    const int g = t >> 6;     // wave 0..3
    const int l = t & 63;     // lane

    __shared__ int   list[BATCH];                   // 8 KB worst case
    __shared__ int   lcount;
    __shared__ __align__(16) float xs[S][NHID];     // 16 KB
    __shared__ __align__(16) float part[4][S][H0];  // 32 KB
    __shared__ float redm[4], reds[4];
    __shared__ float ptop[S], pbot[S];

    // ---- build this parent's sample list (order within group irrelevant)
    if (t == 0) lcount = 0;
    __syncthreads();
    for (int i = t; i < BATCH; i += 256) {
        if (parents[i] == p) {
            int pos = atomicAdd(&lcount, 1);
            list[pos] = i;
        }
    }
    __syncthreads();
    const int n = lcount;
    if (n == 0) return;

    for (int base = 0; base < n; base += S) {
        const int rem = min(S, n - base);

        // ---- cooperative load of up to 8 x-rows (padded slots replicate last)
        for (int s = 0; s < S; ++s) {
            const int idx = list[base + min(s, rem - 1)];
            ((float2*)xs[s])[t] = ((const float2*)(x + (size_t)idx * NHID))[t];
        }
        __syncthreads();

        for (int pass = 0; pass < 2; ++pass) {
            const float* W    = pass ? botW + (size_t)p * NHID * H1 : topW;
            const float* bias = pass ? botb + (size_t)p * H1        : topb;

            // ---- partial GEMV: 128 K-steps, 4 classes/lane, 8 samples
            float4 acc[S];
            #pragma unroll
            for (int s = 0; s < S; ++s) acc[s] = make_float4(0.f, 0.f, 0.f, 0.f);

            const float* Wp = W + (size_t)(g * 128) * H0 + 4 * l;
            #pragma unroll 8
            for (int d = 0; d < 128; ++d) {
                const float4 w = *(const float4*)Wp;
                Wp += H0;
                #pragma unroll
                for (int s = 0; s < S; ++s) {
                    const float xv = xs[s][g * 128 + d];
                    acc[s].x = fmaf(xv, w.x, acc[s].x);
                    acc[s].y = fmaf(xv, w.y, acc[s].y);
                    acc[s].z = fmaf(xv, w.z, acc[s].z);
                    acc[s].w = fmaf(xv, w.w, acc[s].w);
                }
            }
            #pragma unroll
            for (int s = 0; s < S; ++s)
                *(float4*)&part[g][s][4 * l] = acc[s];
            __syncthreads();

            // ---- softmax, Round-1 structure: thread t owns class t
            for (int s = 0; s < rem; ++s) {
                const float logit = part[0][s][t] + part[1][s][t]
                                  + part[2][s][t] + part[3][s][t] + bias[t];

                float m = logit;
                #pragma unroll
                for (int off = 32; off > 0; off >>= 1)
                    m = fmaxf(m, __shfl_xor(m, off, 64));
                if (l == 0) redm[g] = m;
                __syncthreads();
                m = fmaxf(fmaxf(redm[0], redm[1]), fmaxf(redm[2], redm[3]));

                const float e = expf(logit - m);
                float sum = e;
                #pragma unroll
                for (int off = 32; off > 0; off >>= 1)
                    sum += __shfl_xor(sum, off, 64);
                if (l == 0) reds[g] = sum;
                __syncthreads();
                sum = reds[0] + reds[1] + reds[2] + reds[3];

                const int tgt = pass ? labels[list[base + s]] : p;
                if (t == tgt) (pass ? pbot : ptop)[s] = e / sum;
            }
            __syncthreads();   // ptop/pbot visible; part[] safe to overwrite
        }

        if (t < rem) {
            const int idx = list[base + t];
            out[idx] = ptop[t] * pbot[t];
        }
        __syncthreads();       // xs/part safe to overwrite next tile
    }
}

extern "C" void kernel_launch(void* const* d_in, const int* in_sizes, int n_in,
                              void* d_out, int out_size, void* d_ws, size_t ws_size,
                              hipStream_t stream) {
    const float* x       = (const float*)d_in[0];
    const int*   labels  = (const int*)  d_in[1];
    const int*   parents = (const int*)  d_in[2];
    const float* topW    = (const float*)d_in[3];
    const float* topb    = (const float*)d_in[4];
    const float* botW    = (const float*)d_in[5];
    const float* botb    = (const float*)d_in[6];
    float*       out     = (float*)d_out;

    hs_grouped<<<H0, 256, 0, stream>>>(x, labels, parents,
                                       topW, topb, botW, botb, out);
}

// Round 4
// 233.490 us; speedup vs baseline: 1.3864x; 1.1657x over previous
//
#include <hip/hip_runtime.h>

constexpr int BATCH = 2048;
constexpr int NHID  = 512;
constexpr int H0    = 256;
constexpr int H1    = 256;
constexpr int S     = 8;    // samples per tile
constexpr int J     = 3;    // tile-slot blocks per parent (grid = 256*J)

// Block (p = blockIdx&255, j = blockIdx>>8) processes tiles j, j+J, ... of
// parent p's sample group. Sample list built by deterministic ballot scan
// (identical order in every block of the same parent — atomicAdd would NOT
// be; that ordering must match across blocks since tiles partition the list).
// Matmul: wave g covers d in [128g,128g+128), lane l classes 4l..4l+3,
// depth-8 float4 weight prefetch ring; partials -> LDS; R3-verified softmax.
__global__ __launch_bounds__(256) void hs_grouped(
    const float* __restrict__ x,        // [B, NHID]
    const int*   __restrict__ labels,   // [B]
    const int*   __restrict__ parents,  // [B]
    const float* __restrict__ topW,     // [NHID, H0]
    const float* __restrict__ topb,     // [H0]
    const float* __restrict__ botW,     // [H0, NHID, H1]
    const float* __restrict__ botb,     // [H0, H1]
    float*       __restrict__ out)      // [B]
{
    const int p = blockIdx.x & 255;
    const int j = blockIdx.x >> 8;
    const int t = threadIdx.x;
    const int g = t >> 6;     // wave 0..3
    const int l = t & 63;     // lane

    __shared__ int   list[BATCH];                   // 8 KB
    __shared__ int   wcnt[4];
    __shared__ __align__(16) float xs[S][NHID];     // 16 KB
    __shared__ __align__(16) float part[4][S][H0];  // 32 KB
    __shared__ float redm[4], reds[4];
    __shared__ float ptop[S], pbot[S];

    // ---- deterministic ordered list build (ballot prefix scan)
    int running = 0;
    for (int c = 0; c < BATCH; c += 256) {
        const bool match = (parents[c + t] == p);
        const unsigned long long mask = __ballot(match);
        if (l == 0) wcnt[g] = __popcll(mask);
        __syncthreads();
        int off = running;
        for (int w = 0; w < g; ++w) off += wcnt[w];
        if (match)
            list[off + __popcll(mask & ((1ull << l) - 1ull))] = c + t;
        running += wcnt[0] + wcnt[1] + wcnt[2] + wcnt[3];
        __syncthreads();   // wcnt reused next chunk
    }
    const int n = running;
    if (n <= j * S) return;   // uniform exit — no tile for this slot

    for (int base = j * S; base < n; base += J * S) {
        const int rem = min(S, n - base);

        // ---- cooperative load of up to 8 x-rows (padded slots replicate last)
        for (int s = 0; s < S; ++s) {
            const int idx = list[base + min(s, rem - 1)];
            ((float2*)xs[s])[t] = ((const float2*)(x + (size_t)idx * NHID))[t];
        }
        __syncthreads();

        for (int pass = 0; pass < 2; ++pass) {
            const float* W    = pass ? botW + (size_t)p * NHID * H1 : topW;
            const float* bias = pass ? botb + (size_t)p * H1        : topb;

            float4 acc[S];
            #pragma unroll
            for (int s = 0; s < S; ++s) acc[s] = make_float4(0.f, 0.f, 0.f, 0.f);

            // ---- partial GEMV with depth-8 prefetch ring
            const float* Wp = W + (size_t)(g * 128) * H0 + 4 * l;
            float4 wbuf[8];
            #pragma unroll
            for (int i = 0; i < 8; ++i)
                wbuf[i] = *(const float4*)(Wp + i * H0);

            for (int d = 0; d < 128; d += 8) {
                // half A: steps d..d+3
                float4 a0 = wbuf[0], a1 = wbuf[1], a2 = wbuf[2], a3 = wbuf[3];
                if (d + 8 < 128) {
                    #pragma unroll
                    for (int i = 0; i < 4; ++i)
                        wbuf[i] = *(const float4*)(Wp + (d + 8 + i) * H0);
                }
                #pragma unroll
                for (int s = 0; s < S; ++s) {
                    const float4 xv = *(const float4*)&xs[s][g * 128 + d];
                    acc[s].x = fmaf(xv.x, a0.x, acc[s].x);
                    acc[s].y = fmaf(xv.x, a0.y, acc[s].y);
                    acc[s].z = fmaf(xv.x, a0.z, acc[s].z);
                    acc[s].w = fmaf(xv.x, a0.w, acc[s].w);
                    acc[s].x = fmaf(xv.y, a1.x, acc[s].x);
                    acc[s].y = fmaf(xv.y, a1.y, acc[s].y);
                    acc[s].z = fmaf(xv.y, a1.z, acc[s].z);
                    acc[s].w = fmaf(xv.y, a1.w, acc[s].w);
                    acc[s].x = fmaf(xv.z, a2.x, acc[s].x);
                    acc[s].y = fmaf(xv.z, a2.y, acc[s].y);
                    acc[s].z = fmaf(xv.z, a2.z, acc[s].z);
                    acc[s].w = fmaf(xv.z, a2.w, acc[s].w);
                    acc[s].x = fmaf(xv.w, a3.x, acc[s].x);
                    acc[s].y = fmaf(xv.w, a3.y, acc[s].y);
                    acc[s].z = fmaf(xv.w, a3.z, acc[s].z);
                    acc[s].w = fmaf(xv.w, a3.w, acc[s].w);
                }
                // half B: steps d+4..d+7
                float4 b0 = wbuf[4], b1 = wbuf[5], b2 = wbuf[6], b3 = wbuf[7];
                if (d + 12 < 128) {
                    #pragma unroll
                    for (int i = 0; i < 4; ++i)
                        wbuf[4 + i] = *(const float4*)(Wp + (d + 12 + i) * H0);
                }
                #pragma unroll
                for (int s = 0; s < S; ++s) {
                    const float4 xv = *(const float4*)&xs[s][g * 128 + d + 4];
                    acc[s].x = fmaf(xv.x, b0.x, acc[s].x);
                    acc[s].y = fmaf(xv.x, b0.y, acc[s].y);
                    acc[s].z = fmaf(xv.x, b0.z, acc[s].z);
                    acc[s].w = fmaf(xv.x, b0.w, acc[s].w);
                    acc[s].x = fmaf(xv.y, b1.x, acc[s].x);
                    acc[s].y = fmaf(xv.y, b1.y, acc[s].y);
                    acc[s].z = fmaf(xv.y, b1.z, acc[s].z);
                    acc[s].w = fmaf(xv.y, b1.w, acc[s].w);
                    acc[s].x = fmaf(xv.z, b2.x, acc[s].x);
                    acc[s].y = fmaf(xv.z, b2.y, acc[s].y);
                    acc[s].z = fmaf(xv.z, b2.z, acc[s].z);
                    acc[s].w = fmaf(xv.z, b2.w, acc[s].w);
                    acc[s].x = fmaf(xv.w, b3.x, acc[s].x);
                    acc[s].y = fmaf(xv.w, b3.y, acc[s].y);
                    acc[s].z = fmaf(xv.w, b3.z, acc[s].z);
                    acc[s].w = fmaf(xv.w, b3.w, acc[s].w);
                }
            }

            #pragma unroll
            for (int s = 0; s < S; ++s)
                *(float4*)&part[g][s][4 * l] = acc[s];
            __syncthreads();

            // ---- softmax (R3-verified): thread t owns class t
            for (int s = 0; s < rem; ++s) {
                const float logit = part[0][s][t] + part[1][s][t]
                                  + part[2][s][t] + part[3][s][t] + bias[t];

                float m = logit;
                #pragma unroll
                for (int off = 32; off > 0; off >>= 1)
                    m = fmaxf(m, __shfl_xor(m, off, 64));
                if (l == 0) redm[g] = m;
                __syncthreads();
                m = fmaxf(fmaxf(redm[0], redm[1]), fmaxf(redm[2], redm[3]));

                const float e = expf(logit - m);
                float sum = e;
                #pragma unroll
                for (int off = 32; off > 0; off >>= 1)
                    sum += __shfl_xor(sum, off, 64);
                if (l == 0) reds[g] = sum;
                __syncthreads();
                sum = reds[0] + reds[1] + reds[2] + reds[3];

                const int tgt = pass ? labels[list[base + s]] : p;
                if (t == tgt) (pass ? pbot : ptop)[s] = e / sum;
            }
            __syncthreads();   // ptop/pbot visible; part[] safe to overwrite
        }

        if (t < rem) {
            const int idx = list[base + t];
            out[idx] = ptop[t] * pbot[t];
        }
        __syncthreads();       // xs/part safe to overwrite next tile
    }
}

extern "C" void kernel_launch(void* const* d_in, const int* in_sizes, int n_in,
                              void* d_out, int out_size, void* d_ws, size_t ws_size,
                              hipStream_t stream) {
    const float* x       = (const float*)d_in[0];
    const int*   labels  = (const int*)  d_in[1];
    const int*   parents = (const int*)  d_in[2];
    const float* topW    = (const float*)d_in[3];
    const float* topb    = (const float*)d_in[4];
    const float* botW    = (const float*)d_in[5];
    const float* botb    = (const float*)d_in[6];
    float*       out     = (float*)d_out;

    hs_grouped<<<H0 * J, 256, 0, stream>>>(x, labels, parents,
                                           topW, topb, botW, botb, out);
}